// Round 2
// baseline (1331.149 us; speedup 1.0000x reference)
//
#include <hip/hip_runtime.h>

// DualLSTMDecoder: B=256, L=512, E=256, H=128 (4H=512 gates per LSTM).
// R9: remove the serial per-chunk x-GEMM bubble + free the register allocator.
//   - x-GEMM for chunk ch+1 interleaved into the TC recurrence steps: even steps issue
//     global X / W_ih loads for one kc (latency hidden under the ~1.6us step), odd steps
//     pk16-convert + 8 independent MFMAs into persistent ax regs. GxL written once per
//     chunk in the epilogue (merged with the y-phase barrier). Bit-identical numerics
//     (same kc accumulation order as the old serial x-phase).
//   - __launch_bounds__(512,1): grid is 256 blocks on 256 CUs -> only 1 block/CU ever
//     resides; the old (512,2) capped VGPR+AGPR at 256 (whh frags alone are ~128 AGPR)
//     for zero occupancy benefit.
//   - GxL row stride 513 (pad +1 float): rows shift banks by 8/row, breaking the
//     4-way conflicts on the x-epilogue stores (R8: SQ_LDS_BANK_CONFLICT 9.7M).
//   - Quad-split activation, kc-outer h-MFMA, split-f16 W_hh compensation unchanged.
#define B_ 256
#define L_ 512
#define E_ 256
#define H_ 128
#define G4_ 512
#define TC 16
#define NCH 32
#define LDG 513  // GxL row stride in floats (bank-spread pad)

typedef _Float16 half8  __attribute__((ext_vector_type(8)));
typedef float   float4v __attribute__((ext_vector_type(4)));
typedef int     int4v   __attribute__((ext_vector_type(4)));
typedef unsigned int uint32;

// ---- workspace layout (bytes), 1.50 MB ----
static constexpr size_t WT_OFF = 0;                             // f16 [2][8][512][32]  (W_ih tiled)
static constexpr size_t WT_SZ  = (size_t)2 * 8 * 512 * 32 * 2;
static constexpr size_t WH_OFF = WT_OFF + WT_SZ;                // f16 [2][2sel][4][512][32] (W_hh hi/lo)
static constexpr size_t WH_SZ  = (size_t)2 * 2 * 4 * 512 * 32 * 2;
static constexpr size_t YP_OFF = WH_OFF + WH_SZ;                // f32 [B][L]  (lstm1 partial y)
static constexpr size_t YP_SZ  = (size_t)B_ * L_ * 4;
static constexpr size_t WS_NEEDED = YP_OFF + YP_SZ;             // 1,572,864

__device__ __forceinline__ int pk16(float lo, float hi) {
  return __builtin_bit_cast(int, __builtin_amdgcn_cvt_pkrtz(lo, hi));
}
__device__ __forceinline__ float sigf(float x) {
  return __builtin_amdgcn_rcpf(1.f + __builtin_amdgcn_exp2f(-1.44269504f * x));
}
__device__ __forceinline__ float tanhf_(float x) {
  return 1.f - 2.f * __builtin_amdgcn_rcpf(1.f + __builtin_amdgcn_exp2f(2.88539008f * x));
}

// ---------------- phase 0: weight tiling (unchanged) ----------------
__global__ void prep(const float* __restrict__ WihH, const float* __restrict__ WihF,
                     const float* __restrict__ WhhH, const float* __restrict__ WhhF,
                     unsigned char* __restrict__ ws) {
  int id = blockIdx.x * 256 + threadIdx.x;  // 0..524287
  if (id < 262144) {
    int lstm = id >> 17;
    int r = id & 131071;
    int kc = r >> 14;
    int r2 = r & 16383;
    int n = r2 >> 5, k5 = r2 & 31;
    const float* src = lstm ? WihF : WihH;
    ((_Float16*)(ws + WT_OFF))[id] = (_Float16)src[n * E_ + kc * 32 + k5];
  } else {
    int id2 = id - 262144;
    int lstm = id2 >> 17;
    int r = id2 & 131071;
    int sel = r >> 16;
    int r2 = r & 65535;
    int kc = r2 >> 14;
    int r3 = r2 & 16383;
    int n = r3 >> 5, k5 = r3 & 31;
    const float* src = lstm ? WhhF : WhhH;
    float wv = src[n * H_ + kc * 32 + k5];
    _Float16 hi = (_Float16)wv;
    _Float16 o = sel ? (_Float16)((wv - (float)hi) * 4096.f) : hi;
    ((_Float16*)(ws + WH_OFF))[id2] = o;
  }
}

// ---------------- fused ----------------
__global__ __launch_bounds__(512, 1) void fused(
    const float* __restrict__ Xh, const float* __restrict__ Xf,
    const float* __restrict__ bihH, const float* __restrict__ bhhH,
    const float* __restrict__ bihF, const float* __restrict__ bhhF,
    const float* __restrict__ Wffn, unsigned char* __restrict__ ws,
    float* __restrict__ out) {
  const int bp = blockIdx.x, lstm = blockIdx.y;
  const int tid = threadIdx.x;
  const int w = tid >> 6, lane = tid & 63, quad = lane >> 4, l15 = lane & 15;
  __shared__ float GxL[32 * LDG];              // [t*2+b rows][513] fp32 (bias folded), 64.1 KB
  __shared__ _Float16 hA2[2][512];             // dbuf A-frag src [gk][m][8], 2x1 KB
  __shared__ float hist[TC * 2 * 128];         // h fp32 per step, 16 KB
  __shared__ float ybuf[2 * 512];              // y accum, 4 KB

  // --- stationary: W_hh frags (gate-remapped rows g = nt*128 + w*16 + l15), bias, wf ---
  const int u = w * 16 + l15;  // unit owned by this lane (per-quad copy)
  const int gk = u >> 3, jj = u & 7;
  const unsigned char* WH = ws + WH_OFF;
  half8 whh[2][4][4];  // [sel][nt=type][kc]
#pragma unroll
  for (int sel = 0; sel < 2; ++sel)
#pragma unroll
    for (int nt = 0; nt < 4; ++nt)
#pragma unroll
      for (int kc = 0; kc < 4; ++kc) {
        size_t byte =
            (size_t)(((lstm * 2 + sel) * 4 + kc) * 512 + (nt * 128 + u)) * 64 + quad * 16;
        whh[sel][nt][kc] = *(const half8*)(WH + byte);
      }
  float bias4[4];
#pragma unroll
  for (int nt = 0; nt < 4; ++nt) {
    int g = nt * 128 + u;
    bias4[nt] = lstm ? (bihF[g] + bhhF[g]) : (bihH[g] + bhhH[g]);
  }
  const float wf0 = Wffn[lstm * 128 + 2 * lane];
  const float wf1 = Wffn[lstm * 128 + 2 * lane + 1];
  const float* Xb0 = (lstm ? Xf : Xh) + (size_t)(2 * bp) * L_ * E_;
  const float* Xb1 = Xb0 + (size_t)L_ * E_;
  const unsigned char* WT = ws + WT_OFF + (size_t)lstm * 262144;
  float* yp1 = (float*)(ws + YP_OFF);
  float* ypout = (lstm == 0) ? (out + (size_t)(2 * bp) * L_) : (yp1 + (size_t)(2 * bp) * L_);

  float cst = 0.f;  // cell state: quad0 lanes -> batch0, quad1 lanes -> batch1
  const float s_lo = 1.f / 4096.f;

  // ======== prologue: chunk-0 x-GEMM (serial, one time) ========
  {
    float4v ax0[2][4];
#pragma unroll
    for (int mt = 0; mt < 2; ++mt)
#pragma unroll
      for (int nt = 0; nt < 4; ++nt) ax0[mt][nt] = (float4v){0.f, 0.f, 0.f, 0.f};
#pragma unroll 2
    for (int kc = 0; kc < 8; ++kc) {
      const float* xa0 = Xb0 + (size_t)l15 * E_ + kc * 32 + quad * 8;
      const float* xa1 = Xb1 + (size_t)l15 * E_ + kc * 32 + quad * 8;
      float4v u0 = *(const float4v*)xa0, u1 = *(const float4v*)(xa0 + 4);
      float4v v0 = *(const float4v*)xa1, v1 = *(const float4v*)(xa1 + 4);
      int4v ai;
      ai[0] = pk16(u0[0], u0[1]); ai[1] = pk16(u0[2], u0[3]);
      ai[2] = pk16(u1[0], u1[1]); ai[3] = pk16(u1[2], u1[3]);
      half8 A0 = __builtin_bit_cast(half8, ai);
      ai[0] = pk16(v0[0], v0[1]); ai[1] = pk16(v0[2], v0[3]);
      ai[2] = pk16(v1[0], v1[1]); ai[3] = pk16(v1[2], v1[3]);
      half8 A1 = __builtin_bit_cast(half8, ai);
#pragma unroll
      for (int nt = 0; nt < 4; ++nt) {
        const unsigned char* bptr =
            WT + (size_t)kc * 32768 + (size_t)(nt * 128 + u) * 64 + quad * 16;
        half8 bf = *(const half8*)bptr;
        ax0[0][nt] = __builtin_amdgcn_mfma_f32_16x16x32_f16(A0, bf, ax0[0][nt], 0, 0, 0);
        ax0[1][nt] = __builtin_amdgcn_mfma_f32_16x16x32_f16(A1, bf, ax0[1][nt], 0, 0, 0);
      }
    }
#pragma unroll
    for (int mt = 0; mt < 2; ++mt)
#pragma unroll
      for (int nt = 0; nt < 4; ++nt) {
        int colg = nt * 128 + u;
        float bb = bias4[nt];
#pragma unroll
        for (int rg = 0; rg < 4; ++rg)
          GxL[((quad * 4 + rg) * 2 + mt) * LDG + colg] = ax0[mt][nt][rg] + bb;
      }
  }
  __syncthreads();

  // persistent x-pipeline state (chunk ch computes x-GEMM of chunk ch+1)
  float4v ax[2][4];
#pragma unroll
  for (int mt = 0; mt < 2; ++mt)
#pragma unroll
    for (int nt = 0; nt < 4; ++nt) ax[mt][nt] = (float4v){0.f, 0.f, 0.f, 0.f};
  float4v xu0, xu1, xv0, xv1;          // in-flight X loads (issued even step, used odd)
  half8 bfx0, bfx1, bfx2, bfx3;        // in-flight W_ih frags

  for (int ch = 0; ch < NCH; ++ch) {
    const bool hasx = (ch + 1 < NCH);
    const float* Xn0 = Xb0 + (size_t)((ch + 1) * TC + l15) * E_;
    const float* Xn1 = Xn0 + (size_t)L_ * E_;

    // ======== TC recurrence steps, ONE barrier each; x-GEMM slices interleaved ========
    for (int tl = 0; tl < TC; ++tl) {
      const int st = ch * TC + tl;

      // x-slice A: even step -> issue next-chunk loads for kc = tl/2 (latency hidden
      // under this whole step; consumed next step)
      if (hasx && !(tl & 1)) {
        const int k = tl >> 1;
        const float* xa0 = Xn0 + k * 32 + quad * 8;
        const float* xa1 = Xn1 + k * 32 + quad * 8;
        xu0 = *(const float4v*)xa0; xu1 = *(const float4v*)(xa0 + 4);
        xv0 = *(const float4v*)xa1; xv1 = *(const float4v*)(xa1 + 4);
        const unsigned char* bb = WT + (size_t)k * 32768 + (size_t)u * 64 + quad * 16;
        bfx0 = *(const half8*)(bb);
        bfx1 = *(const half8*)(bb + 128 * 64);
        bfx2 = *(const half8*)(bb + 256 * 64);
        bfx3 = *(const half8*)(bb + 384 * 64);
      }

      // Gx prefetch (independent of h-chain; bias already folded in)
      const float* gp = &GxL[(tl * 2 + (quad & 1)) * LDG + u];
      float gx0 = gp[0], gx1 = gp[128], gx2 = gp[256], gx3 = gp[384];

      float4v r1[4], r2[4];
      if (st) {
        const _Float16* hAr = hA2[st & 1];
        half8 hfr[4];
#pragma unroll
        for (int kc = 0; kc < 4; ++kc)
          hfr[kc] = *(const half8*)&hAr[((kc * 4 + quad) * 4 + (l15 & 3)) * 8];
        const float4v z = (float4v){0.f, 0.f, 0.f, 0.f};
        // kc-outer: 8 independent chains, dep distance 8 -> pipe-throughput bound
#pragma unroll
        for (int nt = 0; nt < 4; ++nt) {
          r1[nt] = __builtin_amdgcn_mfma_f32_16x16x32_f16(hfr[0], whh[0][nt][0], z, 0, 0, 0);
          r2[nt] = __builtin_amdgcn_mfma_f32_16x16x32_f16(hfr[0], whh[1][nt][0], z, 0, 0, 0);
        }
#pragma unroll
        for (int kc = 1; kc < 4; ++kc)
#pragma unroll
          for (int nt = 0; nt < 4; ++nt) {
            r1[nt] = __builtin_amdgcn_mfma_f32_16x16x32_f16(hfr[kc], whh[0][nt][kc], r1[nt], 0, 0, 0);
            r2[nt] = __builtin_amdgcn_mfma_f32_16x16x32_f16(hfr[kc], whh[1][nt][kc], r2[nt], 0, 0, 0);
          }
      } else {
#pragma unroll
        for (int nt = 0; nt < 4; ++nt) {
          r1[nt] = (float4v){0.f, 0.f, 0.f, 0.f};
          r2[nt] = (float4v){0.f, 0.f, 0.f, 0.f};
        }
      }

      // x-slice B: odd step -> convert prev-step loads + 8 independent MFMAs into ax
      // (trails the h-MFMAs; overlaps the activation VALU window)
      if (hasx && (tl & 1)) {
        int4v ai;
        ai[0] = pk16(xu0[0], xu0[1]); ai[1] = pk16(xu0[2], xu0[3]);
        ai[2] = pk16(xu1[0], xu1[1]); ai[3] = pk16(xu1[2], xu1[3]);
        half8 A0 = __builtin_bit_cast(half8, ai);
        ai[0] = pk16(xv0[0], xv0[1]); ai[1] = pk16(xv0[2], xv0[3]);
        ai[2] = pk16(xv1[0], xv1[1]); ai[3] = pk16(xv1[2], xv1[3]);
        half8 A1 = __builtin_bit_cast(half8, ai);
        ax[0][0] = __builtin_amdgcn_mfma_f32_16x16x32_f16(A0, bfx0, ax[0][0], 0, 0, 0);
        ax[1][0] = __builtin_amdgcn_mfma_f32_16x16x32_f16(A1, bfx0, ax[1][0], 0, 0, 0);
        ax[0][1] = __builtin_amdgcn_mfma_f32_16x16x32_f16(A0, bfx1, ax[0][1], 0, 0, 0);
        ax[1][1] = __builtin_amdgcn_mfma_f32_16x16x32_f16(A1, bfx1, ax[1][1], 0, 0, 0);
        ax[0][2] = __builtin_amdgcn_mfma_f32_16x16x32_f16(A0, bfx2, ax[0][2], 0, 0, 0);
        ax[1][2] = __builtin_amdgcn_mfma_f32_16x16x32_f16(A1, bfx2, ax[1][2], 0, 0, 0);
        ax[0][3] = __builtin_amdgcn_mfma_f32_16x16x32_f16(A0, bfx3, ax[0][3], 0, 0, 0);
        ax[1][3] = __builtin_amdgcn_mfma_f32_16x16x32_f16(A1, bfx3, ax[1][3], 0, 0, 0);
      }

      // Quad-split activation: A-rows replicate period-4, so quad1 regs == quad0 regs.
      // quad0 handles batch0, quad1 handles batch1 (lane<32 -> single SIMD-32 pass).
      if (quad < 2) {
        const int b = quad;
        const bool q1 = (b != 0);
        float p0 = (q1 ? r1[0][1] : r1[0][0]) + s_lo * ((q1 ? r1[0][3] : r1[0][2]) + (q1 ? r2[0][1] : r2[0][0])) + gx0;
        float p1 = (q1 ? r1[1][1] : r1[1][0]) + s_lo * ((q1 ? r1[1][3] : r1[1][2]) + (q1 ? r2[1][1] : r2[1][0])) + gx1;
        float p2 = (q1 ? r1[2][1] : r1[2][0]) + s_lo * ((q1 ? r1[2][3] : r1[2][2]) + (q1 ? r2[2][1] : r2[2][0])) + gx2;
        float p3 = (q1 ? r1[3][1] : r1[3][0]) + s_lo * ((q1 ? r1[3][3] : r1[3][2]) + (q1 ? r2[3][1] : r2[3][0])) + gx3;
        float iv = sigf(p0), fv = sigf(p1);
        float gg = tanhf_(p2), ov = sigf(p3);
        cst = fv * cst + iv * gg;
        float h = ov * tanhf_(cst);
        _Float16 hh = (_Float16)h;
        _Float16 hl = (_Float16)((h - (float)hh) * 4096.f);
        _Float16* hAw = hA2[(st + 1) & 1];
        hAw[(gk * 4 + b) * 8 + jj] = hh;          // hi row for batch b
        hAw[(gk * 4 + 2 + b) * 8 + jj] = hl;      // lo row for batch b
        hist[(tl * 2 + b) * 128 + u] = h;
      }
      __syncthreads();
    }

    // ======== per-chunk epilogue: y dots + GxL publish for chunk ch+1, one barrier ====
#pragma unroll
    for (int i = 0; i < 4; ++i) {
      int d = w * 4 + i;
      int tl = d >> 1, b = d & 1;
      float y = wf0 * hist[(tl * 2 + b) * 128 + 2 * lane] +
                wf1 * hist[(tl * 2 + b) * 128 + 2 * lane + 1];
      y += __shfl_xor(y, 1);
      y += __shfl_xor(y, 2);
      y += __shfl_xor(y, 4);
      y += __shfl_xor(y, 8);
      y += __shfl_xor(y, 16);
      y += __shfl_xor(y, 32);
      if (lane == 0) ybuf[b * 512 + ch * TC + tl] = y;
    }
    if (hasx) {
#pragma unroll
      for (int mt = 0; mt < 2; ++mt)
#pragma unroll
        for (int nt = 0; nt < 4; ++nt) {
          int colg = nt * 128 + u;
          float bb = bias4[nt];
#pragma unroll
          for (int rg = 0; rg < 4; ++rg)
            GxL[((quad * 4 + rg) * 2 + mt) * LDG + colg] = ax[mt][nt][rg] + bb;
          ax[mt][nt] = (float4v){0.f, 0.f, 0.f, 0.f};
        }
    }
    __syncthreads();  // GxL(ch+1)/ybuf/hist stable before next chunk
  }
  // single flush of y (the only global stores besides combine)
  ypout[tid] = ybuf[tid];
  ypout[512 + tid] = ybuf[512 + tid];
}

// ---------------- combine: out += yp1 + b_ffn ----------------
__global__ __launch_bounds__(256) void combine(const unsigned char* __restrict__ ws,
                                               const float* __restrict__ bffn,
                                               float* __restrict__ out) {
  int i = blockIdx.x * 256 + threadIdx.x;  // 0..131071
  const float* yp1 = (const float*)(ws + YP_OFF);
  out[i] = out[i] + yp1[i] + bffn[0];
}

extern "C" void kernel_launch(void* const* d_in, const int* in_sizes, int n_in,
                              void* d_out, int out_size, void* d_ws, size_t ws_size,
                              hipStream_t stream) {
  (void)in_sizes; (void)n_in; (void)out_size;
  const float* histX = (const float*)d_in[0];
  const float* futX  = (const float*)d_in[1];
  const float* WihH  = (const float*)d_in[2];
  const float* WhhH  = (const float*)d_in[3];
  const float* bihH  = (const float*)d_in[4];
  const float* bhhH  = (const float*)d_in[5];
  const float* WihF  = (const float*)d_in[6];
  const float* WhhF  = (const float*)d_in[7];
  const float* bihF  = (const float*)d_in[8];
  const float* bhhF  = (const float*)d_in[9];
  const float* Wffn  = (const float*)d_in[10];
  const float* bffn  = (const float*)d_in[11];
  unsigned char* ws = (unsigned char*)d_ws;
  float* out = (float*)d_out;

  if (ws_size < WS_NEEDED) return;

  prep<<<2048, 256, 0, stream>>>(WihH, WihF, WhhH, WhhF, ws);
  fused<<<dim3(B_ / 2, 2), 512, 0, stream>>>(histX, futX, bihH, bhhH, bihF, bhhF, Wffn, ws, out);
  combine<<<512, 256, 0, stream>>>(ws, bffn, out);
}

// Round 3
// 1009.485 us; speedup vs baseline: 1.3186x; 1.3186x over previous
//
#include <hip/hip_runtime.h>

// DualLSTMDecoder: B=256, L=512, E=256, H=128 (4H=512 gates per LSTM).
// R10: revert to R8 structure (R9's step-interleave spilled: live set ~274 regs > 256
// budget -> 900 MB scratch traffic, FETCH 135->920 MB). Register-neutral fixes only:
//   - hA2[0] zero-init replaces the `if (st)` branch (0*W = 0, bit-identical) ->
//     uniform step body, #pragma unroll 4 on the step loop.
//   - Activation nt-split across quad pairs: quads 0/1 compute i,f (b0/b1), quads 2/3
//     compute g,o (rows are quad-replicated so all selects are cndmask). shfl_xor(.,32)
//     returns g,o to the c-owner lanes. Trans issue 10->8/wave, Gx reads 4->2/lane
//     (ds_read2-fusable pair, offset 128). Same sigf/tanhf_ per gate -> same numerics.
//   - GxL row stride 513: x-epilogue stores drop from 4-way to <=2-way conflicts.
//   - y-phase reads hist as float2 (ds_read_b64).
//   - Everything else identical to R8 (849us): launch_bounds(512,2), serial per-chunk
//     x-GEMM (unroll 2), split-f16 W_hh compensation (hi + 2^-12*(lo-terms)).
#define B_ 256
#define L_ 512
#define E_ 256
#define H_ 128
#define G4_ 512
#define TC 16
#define NCH 32
#define LDG 513  // GxL row stride in floats (bank-spread pad)

typedef _Float16 half8  __attribute__((ext_vector_type(8)));
typedef float   float4v __attribute__((ext_vector_type(4)));
typedef int     int4v   __attribute__((ext_vector_type(4)));
typedef unsigned int uint32;

// ---- workspace layout (bytes), 1.50 MB ----
static constexpr size_t WT_OFF = 0;                             // f16 [2][8][512][32]  (W_ih tiled)
static constexpr size_t WT_SZ  = (size_t)2 * 8 * 512 * 32 * 2;
static constexpr size_t WH_OFF = WT_OFF + WT_SZ;                // f16 [2][2sel][4][512][32] (W_hh hi/lo)
static constexpr size_t WH_SZ  = (size_t)2 * 2 * 4 * 512 * 32 * 2;
static constexpr size_t YP_OFF = WH_OFF + WH_SZ;                // f32 [B][L]  (lstm1 partial y)
static constexpr size_t YP_SZ  = (size_t)B_ * L_ * 4;
static constexpr size_t WS_NEEDED = YP_OFF + YP_SZ;             // 1,572,864

__device__ __forceinline__ int pk16(float lo, float hi) {
  return __builtin_bit_cast(int, __builtin_amdgcn_cvt_pkrtz(lo, hi));
}
__device__ __forceinline__ float sigf(float x) {
  return __builtin_amdgcn_rcpf(1.f + __builtin_amdgcn_exp2f(-1.44269504f * x));
}
__device__ __forceinline__ float tanhf_(float x) {
  return 1.f - 2.f * __builtin_amdgcn_rcpf(1.f + __builtin_amdgcn_exp2f(2.88539008f * x));
}

// ---------------- phase 0: weight tiling (unchanged) ----------------
__global__ void prep(const float* __restrict__ WihH, const float* __restrict__ WihF,
                     const float* __restrict__ WhhH, const float* __restrict__ WhhF,
                     unsigned char* __restrict__ ws) {
  int id = blockIdx.x * 256 + threadIdx.x;  // 0..524287
  if (id < 262144) {
    int lstm = id >> 17;
    int r = id & 131071;
    int kc = r >> 14;
    int r2 = r & 16383;
    int n = r2 >> 5, k5 = r2 & 31;
    const float* src = lstm ? WihF : WihH;
    ((_Float16*)(ws + WT_OFF))[id] = (_Float16)src[n * E_ + kc * 32 + k5];
  } else {
    int id2 = id - 262144;
    int lstm = id2 >> 17;
    int r = id2 & 131071;
    int sel = r >> 16;
    int r2 = r & 65535;
    int kc = r2 >> 14;
    int r3 = r2 & 16383;
    int n = r3 >> 5, k5 = r3 & 31;
    const float* src = lstm ? WhhF : WhhH;
    float wv = src[n * H_ + kc * 32 + k5];
    _Float16 hi = (_Float16)wv;
    _Float16 o = sel ? (_Float16)((wv - (float)hi) * 4096.f) : hi;
    ((_Float16*)(ws + WH_OFF))[id2] = o;
  }
}

// ---------------- fused ----------------
__global__ __launch_bounds__(512, 2) void fused(
    const float* __restrict__ Xh, const float* __restrict__ Xf,
    const float* __restrict__ bihH, const float* __restrict__ bhhH,
    const float* __restrict__ bihF, const float* __restrict__ bhhF,
    const float* __restrict__ Wffn, unsigned char* __restrict__ ws,
    float* __restrict__ out) {
  const int bp = blockIdx.x, lstm = blockIdx.y;
  const int tid = threadIdx.x;
  const int w = tid >> 6, lane = tid & 63, quad = lane >> 4, l15 = lane & 15;
  __shared__ float GxL[32 * LDG];              // [t*2+b rows][513] fp32 (bias folded), 64.1 KB
  __shared__ _Float16 hA2[2][512];             // dbuf A-frag src [gk][m][8], 2x1 KB
  __shared__ float hist[TC * 2 * 128];         // h fp32 per step, 16 KB
  __shared__ float ybuf[2 * 512];              // y accum, 4 KB

  // --- stationary: W_hh frags (gate-remapped rows g = nt*128 + w*16 + l15), bias, wf ---
  const int u = w * 16 + l15;  // unit owned by this lane (per-quad copy)
  const int gk = u >> 3, jj = u & 7;
  const unsigned char* WH = ws + WH_OFF;
  half8 whh[2][4][4];  // [sel][nt=type][kc]
#pragma unroll
  for (int sel = 0; sel < 2; ++sel)
#pragma unroll
    for (int nt = 0; nt < 4; ++nt)
#pragma unroll
      for (int kc = 0; kc < 4; ++kc) {
        size_t byte =
            (size_t)(((lstm * 2 + sel) * 4 + kc) * 512 + (nt * 128 + u)) * 64 + quad * 16;
        whh[sel][nt][kc] = *(const half8*)(WH + byte);
      }
  float bias4[4];
#pragma unroll
  for (int nt = 0; nt < 4; ++nt) {
    int g = nt * 128 + u;
    bias4[nt] = lstm ? (bihF[g] + bhhF[g]) : (bihH[g] + bhhH[g]);
  }
  const float wf0 = Wffn[lstm * 128 + 2 * lane];
  const float wf1 = Wffn[lstm * 128 + 2 * lane + 1];
  const float* Xb0 = (lstm ? Xf : Xh) + (size_t)(2 * bp) * L_ * E_;
  const float* Xb1 = Xb0 + (size_t)L_ * E_;
  const unsigned char* WT = ws + WT_OFF + (size_t)lstm * 262144;
  float* yp1 = (float*)(ws + YP_OFF);
  float* ypout = (lstm == 0) ? (out + (size_t)(2 * bp) * L_) : (yp1 + (size_t)(2 * bp) * L_);

  float cst = 0.f;  // cell state: quad0 lanes -> batch0, quad1 lanes -> batch1
  const float s_lo = 1.f / 4096.f;

  // h_0 = 0: zero hA2[0] so step 0 takes the uniform MFMA path (0*W = 0)
  hA2[0][tid] = (_Float16)0.f;

  for (int ch = 0; ch < NCH; ++ch) {
    // ======== x-GEMM: GxL[t][b][g] = x@Wih^T + bias (direct-from-global fragments) ====
    float4v ax[2][4];
#pragma unroll
    for (int mt = 0; mt < 2; ++mt)
#pragma unroll
      for (int nt = 0; nt < 4; ++nt) ax[mt][nt] = (float4v){0.f, 0.f, 0.f, 0.f};
#pragma unroll 2
    for (int kc = 0; kc < 8; ++kc) {
      const float* xa0 = Xb0 + (size_t)(ch * TC + l15) * E_ + kc * 32 + quad * 8;
      const float* xa1 = Xb1 + (size_t)(ch * TC + l15) * E_ + kc * 32 + quad * 8;
      float4v u0 = *(const float4v*)xa0, u1 = *(const float4v*)(xa0 + 4);
      float4v v0 = *(const float4v*)xa1, v1 = *(const float4v*)(xa1 + 4);
      int4v ai;
      ai[0] = pk16(u0[0], u0[1]); ai[1] = pk16(u0[2], u0[3]);
      ai[2] = pk16(u1[0], u1[1]); ai[3] = pk16(u1[2], u1[3]);
      half8 A0 = __builtin_bit_cast(half8, ai);
      ai[0] = pk16(v0[0], v0[1]); ai[1] = pk16(v0[2], v0[3]);
      ai[2] = pk16(v1[0], v1[1]); ai[3] = pk16(v1[2], v1[3]);
      half8 A1 = __builtin_bit_cast(half8, ai);
#pragma unroll
      for (int nt = 0; nt < 4; ++nt) {
        const unsigned char* bptr =
            WT + (size_t)kc * 32768 + (size_t)(nt * 128 + u) * 64 + quad * 16;
        half8 bf = *(const half8*)bptr;
        ax[0][nt] = __builtin_amdgcn_mfma_f32_16x16x32_f16(A0, bf, ax[0][nt], 0, 0, 0);
        ax[1][nt] = __builtin_amdgcn_mfma_f32_16x16x32_f16(A1, bf, ax[1][nt], 0, 0, 0);
      }
    }
#pragma unroll
    for (int mt = 0; mt < 2; ++mt)
#pragma unroll
      for (int nt = 0; nt < 4; ++nt) {
        int colg = nt * 128 + u;
        float bb = bias4[nt];
#pragma unroll
        for (int rg = 0; rg < 4; ++rg)
          GxL[((quad * 4 + rg) * 2 + mt) * LDG + colg] = ax[mt][nt][rg] + bb;
      }
    __syncthreads();

    // ======== TC recurrence steps, ONE barrier each, uniform body ========
#pragma unroll 4
    for (int tl = 0; tl < TC; ++tl) {
      const int st = ch * TC + tl;
      const bool hi2 = (quad >= 2);      // quads 2,3 -> gates g,o; quads 0,1 -> i,f
      const int bq = quad & 1;           // batch owned by this quad

      // Gx prefetch: 2 reads/lane (ntA, ntB = ntA+1), ds_read2-fusable (offset 128)
      const float* gp = &GxL[(tl * 2 + bq) * LDG + u + (hi2 ? 256 : 0)];
      float gxA = gp[0], gxB = gp[128];

      const _Float16* hAr = hA2[st & 1];
      half8 hfr[4];
#pragma unroll
      for (int kc = 0; kc < 4; ++kc)
        hfr[kc] = *(const half8*)&hAr[((kc * 4 + quad) * 4 + (l15 & 3)) * 8];
      const float4v z = (float4v){0.f, 0.f, 0.f, 0.f};
      float4v r1[4], r2[4];
      // kc-outer: 8 independent chains, dep distance 8 -> pipe-throughput bound
#pragma unroll
      for (int nt = 0; nt < 4; ++nt) {
        r1[nt] = __builtin_amdgcn_mfma_f32_16x16x32_f16(hfr[0], whh[0][nt][0], z, 0, 0, 0);
        r2[nt] = __builtin_amdgcn_mfma_f32_16x16x32_f16(hfr[0], whh[1][nt][0], z, 0, 0, 0);
      }
#pragma unroll
      for (int kc = 1; kc < 4; ++kc)
#pragma unroll
        for (int nt = 0; nt < 4; ++nt) {
          r1[nt] = __builtin_amdgcn_mfma_f32_16x16x32_f16(hfr[kc], whh[0][nt][kc], r1[nt], 0, 0, 0);
          r2[nt] = __builtin_amdgcn_mfma_f32_16x16x32_f16(hfr[kc], whh[1][nt][kc], r2[nt], 0, 0, 0);
        }

      // nt-split activation: all selects constant-index + cndmask (no scratch).
      // ntA = hi2?2:0 (i or g), ntB = hi2?3:1 (f or o); batch = bq.
      float hiA  = hi2 ? (bq ? r1[2][1] : r1[2][0]) : (bq ? r1[0][1] : r1[0][0]);
      float loA  = hi2 ? (bq ? r1[2][3] : r1[2][2]) : (bq ? r1[0][3] : r1[0][2]);
      float wlA  = hi2 ? (bq ? r2[2][1] : r2[2][0]) : (bq ? r2[0][1] : r2[0][0]);
      float hiB  = hi2 ? (bq ? r1[3][1] : r1[3][0]) : (bq ? r1[1][1] : r1[1][0]);
      float loB  = hi2 ? (bq ? r1[3][3] : r1[3][2]) : (bq ? r1[1][3] : r1[1][2]);
      float wlB  = hi2 ? (bq ? r2[3][1] : r2[3][0]) : (bq ? r2[1][1] : r2[1][0]);
      float pA = hiA + s_lo * (loA + wlA) + gxA;
      float pB = hiB + s_lo * (loB + wlB) + gxB;
      float vA = hi2 ? tanhf_(pA) : sigf(pA);  // g (tanh) on quads 2,3; i on 0,1
      float vB = sigf(pB);                     // f on quads 0,1; o on quads 2,3
      float gg = __shfl_xor(vA, 32);           // quads 0,1 receive g of (u, bq)
      float oo = __shfl_xor(vB, 32);           // quads 0,1 receive o of (u, bq)
      if (quad < 2) {                          // c/h owners: quad0->b0, quad1->b1
        cst = vB * cst + vA * gg;              // f*c + i*g  (same op order as R8)
        float h = oo * tanhf_(cst);
        _Float16 hh = (_Float16)h;
        _Float16 hl = (_Float16)((h - (float)hh) * 4096.f);
        _Float16* hAw = hA2[(st + 1) & 1];
        hAw[(gk * 4 + bq) * 8 + jj] = hh;      // hi row for batch bq
        hAw[(gk * 4 + 2 + bq) * 8 + jj] = hl;  // lo row for batch bq
        hist[(tl * 2 + bq) * 128 + u] = h;
      }
      __syncthreads();
    }

    // ======== per-chunk y phase: 32 dots over 8 waves ========
#pragma unroll
    for (int i = 0; i < 4; ++i) {
      int d = w * 4 + i;
      int tl = d >> 1, b = d & 1;
      float2 hv = *(const float2*)&hist[(tl * 2 + b) * 128 + 2 * lane];
      float y = wf0 * hv.x + wf1 * hv.y;
      y += __shfl_xor(y, 1);
      y += __shfl_xor(y, 2);
      y += __shfl_xor(y, 4);
      y += __shfl_xor(y, 8);
      y += __shfl_xor(y, 16);
      y += __shfl_xor(y, 32);
      if (lane == 0) ybuf[b * 512 + ch * TC + tl] = y;
    }
    __syncthreads();  // ybuf/hist/GxL stable before next chunk
  }
  // single flush of y (the only global stores besides combine)
  ypout[tid] = ybuf[tid];
  ypout[512 + tid] = ybuf[512 + tid];
}

// ---------------- combine: out += yp1 + b_ffn ----------------
__global__ __launch_bounds__(256) void combine(const unsigned char* __restrict__ ws,
                                               const float* __restrict__ bffn,
                                               float* __restrict__ out) {
  int i = blockIdx.x * 256 + threadIdx.x;  // 0..131071
  const float* yp1 = (const float*)(ws + YP_OFF);
  out[i] = out[i] + yp1[i] + bffn[0];
}

extern "C" void kernel_launch(void* const* d_in, const int* in_sizes, int n_in,
                              void* d_out, int out_size, void* d_ws, size_t ws_size,
                              hipStream_t stream) {
  (void)in_sizes; (void)n_in; (void)out_size;
  const float* histX = (const float*)d_in[0];
  const float* futX  = (const float*)d_in[1];
  const float* WihH  = (const float*)d_in[2];
  const float* WhhH  = (const float*)d_in[3];
  const float* bihH  = (const float*)d_in[4];
  const float* bhhH  = (const float*)d_in[5];
  const float* WihF  = (const float*)d_in[6];
  const float* WhhF  = (const float*)d_in[7];
  const float* bihF  = (const float*)d_in[8];
  const float* bihF2 = (const float*)d_in[9];
  const float* Wffn  = (const float*)d_in[10];
  const float* bffn  = (const float*)d_in[11];
  unsigned char* ws = (unsigned char*)d_ws;
  float* out = (float*)d_out;

  if (ws_size < WS_NEEDED) return;

  prep<<<2048, 256, 0, stream>>>(WihH, WihF, WhhH, WhhF, ws);
  fused<<<dim3(B_ / 2, 2), 512, 0, stream>>>(histX, futX, bihH, bhhH, bihF, bihF2, Wffn, ws, out);
  combine<<<512, 256, 0, stream>>>(ws, bffn, out);
}

// Round 4
// 794.357 us; speedup vs baseline: 1.6758x; 1.2708x over previous
//
#include <hip/hip_runtime.h>

// DualLSTMDecoder: B=256, L=512, E=256, H=128 (4H=512 gates per LSTM).
// R11: de-serialize around the R8 core (874us R10 / 849us R8).
//   - __launch_bounds__(512,1): grid=256 blocks on 256 CUs -> always 1 block/CU; the
//     old (512,2) capped regs at 256/wave, forcing whh (128 regs) into AGPR with
//     per-MFMA copy-back (suspected source of the 955cy/SIMD/step VALU mystery).
//     Unlike R9, NO new cross-barrier register state (staging holds 2 VGPRs only).
//   - X staged to LDS as f16 (2 floats/thread/step, tl<8, pk16 with the same RTZ
//     pairing -> bit-identical): removes the x-phase's ~4 serial HBM latencies/chunk
//     and its 128 pk16/thread. x-phase A-frags become single ds_read_b128.
//   - Per-step barrier = inline-asm "s_waitcnt lgkmcnt(0); s_barrier" (no vmcnt(0)
//     drain -> staged global loads stay in flight across step barriers).
//   - Activation reverted to R8 quad-split (R10's shfl variant regressed 25us);
//     keep R10's uniform body (hA2[0] zero-init), GxL stride 513, float2 y reads.
#define B_ 256
#define L_ 512
#define E_ 256
#define H_ 128
#define G4_ 512
#define TC 16
#define NCH 32
#define LDG 513  // GxL row stride in floats

typedef _Float16 half8  __attribute__((ext_vector_type(8)));
typedef float   float4v __attribute__((ext_vector_type(4)));
typedef int     int4v   __attribute__((ext_vector_type(4)));

// ---- workspace layout (bytes), 1.50 MB ----
static constexpr size_t WT_OFF = 0;                             // f16 [2][8][512][32]  (W_ih tiled)
static constexpr size_t WT_SZ  = (size_t)2 * 8 * 512 * 32 * 2;
static constexpr size_t WH_OFF = WT_OFF + WT_SZ;                // f16 [2][2sel][4][512][32] (W_hh hi/lo)
static constexpr size_t WH_SZ  = (size_t)2 * 2 * 4 * 512 * 32 * 2;
static constexpr size_t YP_OFF = WH_OFF + WH_SZ;                // f32 [B][L]  (lstm1 partial y)
static constexpr size_t YP_SZ  = (size_t)B_ * L_ * 4;
static constexpr size_t WS_NEEDED = YP_OFF + YP_SZ;             // 1,572,864

__device__ __forceinline__ int pk16(float lo, float hi) {
  return __builtin_bit_cast(int, __builtin_amdgcn_cvt_pkrtz(lo, hi));
}
__device__ __forceinline__ float sigf(float x) {
  return __builtin_amdgcn_rcpf(1.f + __builtin_amdgcn_exp2f(-1.44269504f * x));
}
__device__ __forceinline__ float tanhf_(float x) {
  return 1.f - 2.f * __builtin_amdgcn_rcpf(1.f + __builtin_amdgcn_exp2f(2.88539008f * x));
}
__device__ __forceinline__ void step_barrier() {  // lgkm-only: don't drain vmcnt
  asm volatile("s_waitcnt lgkmcnt(0)\n\ts_barrier" ::: "memory");
}

// ---------------- phase 0: weight tiling (unchanged) ----------------
__global__ void prep(const float* __restrict__ WihH, const float* __restrict__ WihF,
                     const float* __restrict__ WhhH, const float* __restrict__ WhhF,
                     unsigned char* __restrict__ ws) {
  int id = blockIdx.x * 256 + threadIdx.x;  // 0..524287
  if (id < 262144) {
    int lstm = id >> 17;
    int r = id & 131071;
    int kc = r >> 14;
    int r2 = r & 16383;
    int n = r2 >> 5, k5 = r2 & 31;
    const float* src = lstm ? WihF : WihH;
    ((_Float16*)(ws + WT_OFF))[id] = (_Float16)src[n * E_ + kc * 32 + k5];
  } else {
    int id2 = id - 262144;
    int lstm = id2 >> 17;
    int r = id2 & 131071;
    int sel = r >> 16;
    int r2 = r & 65535;
    int kc = r2 >> 14;
    int r3 = r2 & 16383;
    int n = r3 >> 5, k5 = r3 & 31;
    const float* src = lstm ? WhhF : WhhH;
    float wv = src[n * H_ + kc * 32 + k5];
    _Float16 hi = (_Float16)wv;
    _Float16 o = sel ? (_Float16)((wv - (float)hi) * 4096.f) : hi;
    ((_Float16*)(ws + WH_OFF))[id2] = o;
  }
}

// ---------------- fused ----------------
__global__ __launch_bounds__(512, 1) void fused(
    const float* __restrict__ Xh, const float* __restrict__ Xf,
    const float* __restrict__ bihH, const float* __restrict__ bhhH,
    const float* __restrict__ bihF, const float* __restrict__ bhhF,
    const float* __restrict__ Wffn, unsigned char* __restrict__ ws,
    float* __restrict__ out) {
  const int bp = blockIdx.x, lstm = blockIdx.y;
  const int tid = threadIdx.x;
  const int w = tid >> 6, lane = tid & 63, quad = lane >> 4, l15 = lane & 15;
  __shared__ float GxL[32 * LDG];              // [t*2+b rows][513] fp32 (bias folded), 64.1 KB
  __shared__ _Float16 hA2[2][512];             // dbuf A-frag src [gk][m][8], 2x1 KB
  __shared__ float hist[TC * 2 * 128];         // h fp32 per step, 16 KB
  __shared__ float ybuf[2 * 512];              // y accum, 4 KB
  __shared__ _Float16 XS[2][16][264];          // next-chunk X tile, f16, padded, 16.5 KB

  // --- stationary: W_hh frags (gate-remapped rows g = nt*128 + w*16 + l15), bias, wf ---
  const int u = w * 16 + l15;  // unit owned by this lane (per-quad copy)
  const int gk = u >> 3, jj = u & 7;
  const unsigned char* WH = ws + WH_OFF;
  half8 whh[2][4][4];  // [sel][nt=type][kc]
#pragma unroll
  for (int sel = 0; sel < 2; ++sel)
#pragma unroll
    for (int nt = 0; nt < 4; ++nt)
#pragma unroll
      for (int kc = 0; kc < 4; ++kc) {
        size_t byte =
            (size_t)(((lstm * 2 + sel) * 4 + kc) * 512 + (nt * 128 + u)) * 64 + quad * 16;
        whh[sel][nt][kc] = *(const half8*)(WH + byte);
      }
  float bias4[4];
#pragma unroll
  for (int nt = 0; nt < 4; ++nt) {
    int g = nt * 128 + u;
    bias4[nt] = lstm ? (bihF[g] + bhhF[g]) : (bihH[g] + bhhH[g]);
  }
  const float wf0 = Wffn[lstm * 128 + 2 * lane];
  const float wf1 = Wffn[lstm * 128 + 2 * lane + 1];
  const float* Xb0 = (lstm ? Xf : Xh) + (size_t)(2 * bp) * L_ * E_;
  const float* Xb1 = Xb0 + (size_t)L_ * E_;
  const unsigned char* WT = ws + WT_OFF + (size_t)lstm * 262144;
  float* yp1 = (float*)(ws + YP_OFF);
  float* ypout = (lstm == 0) ? (out + (size_t)(2 * bp) * L_) : (yp1 + (size_t)(2 * bp) * L_);

  float cst = 0.f;  // cell state: quad0 lanes -> batch0, quad1 lanes -> batch1
  const float s_lo = 1.f / 4096.f;

  // h_0 = 0: zero hA2[0] so step 0 takes the uniform MFMA path (0*W = 0)
  hA2[0][tid] = (_Float16)0.f;

  // ---- prologue: stage chunk-0 X tile into XS (issue all 8 loads, then write) ----
  {
    float2 pv[8];
#pragma unroll
    for (int r = 0; r < 8; ++r) {
      int f = r * 1024 + tid * 2;
      int sb = f >> 12, stt = (f >> 8) & 15, se = f & 255;
      pv[r] = *(const float2*)((sb ? Xb1 : Xb0) + (size_t)stt * E_ + se);
    }
#pragma unroll
    for (int r = 0; r < 8; ++r) {
      int f = r * 1024 + tid * 2;
      int sb = f >> 12, stt = (f >> 8) & 15, se = f & 255;
      *(int*)&XS[sb][stt][se] = pk16(pv[r].x, pv[r].y);
    }
  }
  __syncthreads();

  for (int ch = 0; ch < NCH; ++ch) {
    const bool stg = (ch + 1 < NCH);

    // ======== x-GEMM: GxL = x@Wih^T + bias; A-frags straight from XS (LDS f16) ======
    float4v ax[2][4];
#pragma unroll
    for (int mt = 0; mt < 2; ++mt)
#pragma unroll
      for (int nt = 0; nt < 4; ++nt) ax[mt][nt] = (float4v){0.f, 0.f, 0.f, 0.f};
#pragma unroll 2
    for (int kc = 0; kc < 8; ++kc) {
      half8 A0 = *(const half8*)&XS[0][l15][kc * 32 + quad * 8];
      half8 A1 = *(const half8*)&XS[1][l15][kc * 32 + quad * 8];
#pragma unroll
      for (int nt = 0; nt < 4; ++nt) {
        const unsigned char* bptr =
            WT + (size_t)kc * 32768 + (size_t)(nt * 128 + u) * 64 + quad * 16;
        half8 bf = *(const half8*)bptr;
        ax[0][nt] = __builtin_amdgcn_mfma_f32_16x16x32_f16(A0, bf, ax[0][nt], 0, 0, 0);
        ax[1][nt] = __builtin_amdgcn_mfma_f32_16x16x32_f16(A1, bf, ax[1][nt], 0, 0, 0);
      }
    }
#pragma unroll
    for (int mt = 0; mt < 2; ++mt)
#pragma unroll
      for (int nt = 0; nt < 4; ++nt) {
        int colg = nt * 128 + u;
        float bb = bias4[nt];
#pragma unroll
        for (int rg = 0; rg < 4; ++rg)
          GxL[((quad * 4 + rg) * 2 + mt) * LDG + colg] = ax[mt][nt][rg] + bb;
      }
    __syncthreads();  // GxL visible; XS reads retired (steps may overwrite XS)

    // ======== TC recurrence steps, ONE lgkm-barrier each, uniform body ========
#pragma unroll 4
    for (int tl = 0; tl < TC; ++tl) {
      const int st = ch * TC + tl;

      // staged X load for chunk ch+1 (2 floats/thread, steps 0..7); issued here,
      // consumed after the MFMA block (latency hidden under ~1200cy of MFMA)
      float2 xv;
      int sb = 0, stt = 0, se = 0;
      const bool dostg = stg && (tl < 8);
      if (dostg) {
        int f = tl * 1024 + tid * 2;
        sb = f >> 12; stt = (f >> 8) & 15; se = f & 255;
        xv = *(const float2*)((sb ? Xb1 : Xb0) + (size_t)((ch + 1) * TC + stt) * E_ + se);
      }

      // Gx prefetch (independent of h-chain; bias already folded in)
      const float* gp = &GxL[(tl * 2 + (quad & 1)) * LDG + u];
      float gx0 = gp[0], gx1 = gp[128], gx2 = gp[256], gx3 = gp[384];

      const _Float16* hAr = hA2[st & 1];
      half8 hfr[4];
#pragma unroll
      for (int kc = 0; kc < 4; ++kc)
        hfr[kc] = *(const half8*)&hAr[((kc * 4 + quad) * 4 + (l15 & 3)) * 8];
      const float4v z = (float4v){0.f, 0.f, 0.f, 0.f};
      float4v r1[4], r2[4];
      // kc-outer: 8 independent chains, dep distance 8 -> pipe-throughput bound
#pragma unroll
      for (int nt = 0; nt < 4; ++nt) {
        r1[nt] = __builtin_amdgcn_mfma_f32_16x16x32_f16(hfr[0], whh[0][nt][0], z, 0, 0, 0);
        r2[nt] = __builtin_amdgcn_mfma_f32_16x16x32_f16(hfr[0], whh[1][nt][0], z, 0, 0, 0);
      }
#pragma unroll
      for (int kc = 1; kc < 4; ++kc)
#pragma unroll
        for (int nt = 0; nt < 4; ++nt) {
          r1[nt] = __builtin_amdgcn_mfma_f32_16x16x32_f16(hfr[kc], whh[0][nt][kc], r1[nt], 0, 0, 0);
          r2[nt] = __builtin_amdgcn_mfma_f32_16x16x32_f16(hfr[kc], whh[1][nt][kc], r2[nt], 0, 0, 0);
        }

      // staged X: convert + park in XS (vmcnt wait lands here, after the MFMAs)
      if (dostg) *(int*)&XS[sb][stt][se] = pk16(xv.x, xv.y);

      // R8 quad-split activation: quad0 -> batch0, quad1 -> batch1, all 4 gates local
      if (quad < 2) {
        const int b = quad;
        const bool q1 = (b != 0);
        float p0 = (q1 ? r1[0][1] : r1[0][0]) + s_lo * ((q1 ? r1[0][3] : r1[0][2]) + (q1 ? r2[0][1] : r2[0][0])) + gx0;
        float p1 = (q1 ? r1[1][1] : r1[1][0]) + s_lo * ((q1 ? r1[1][3] : r1[1][2]) + (q1 ? r2[1][1] : r2[1][0])) + gx1;
        float p2 = (q1 ? r1[2][1] : r1[2][0]) + s_lo * ((q1 ? r1[2][3] : r1[2][2]) + (q1 ? r2[2][1] : r2[2][0])) + gx2;
        float p3 = (q1 ? r1[3][1] : r1[3][0]) + s_lo * ((q1 ? r1[3][3] : r1[3][2]) + (q1 ? r2[3][1] : r2[3][0])) + gx3;
        float iv = sigf(p0), fv = sigf(p1);
        float gg = tanhf_(p2), ov = sigf(p3);
        cst = fv * cst + iv * gg;
        float h = ov * tanhf_(cst);
        _Float16 hh = (_Float16)h;
        _Float16 hl = (_Float16)((h - (float)hh) * 4096.f);
        _Float16* hAw = hA2[(st + 1) & 1];
        hAw[(gk * 4 + b) * 8 + jj] = hh;      // hi row for batch b
        hAw[(gk * 4 + 2 + b) * 8 + jj] = hl;  // lo row for batch b
        hist[(tl * 2 + b) * 128 + u] = h;
      }
      step_barrier();
    }

    // ======== per-chunk y phase: 32 dots over 8 waves ========
#pragma unroll
    for (int i = 0; i < 4; ++i) {
      int d = w * 4 + i;
      int tl = d >> 1, b = d & 1;
      float2 hv = *(const float2*)&hist[(tl * 2 + b) * 128 + 2 * lane];
      float y = wf0 * hv.x + wf1 * hv.y;
      y += __shfl_xor(y, 1);
      y += __shfl_xor(y, 2);
      y += __shfl_xor(y, 4);
      y += __shfl_xor(y, 8);
      y += __shfl_xor(y, 16);
      y += __shfl_xor(y, 32);
      if (lane == 0) ybuf[b * 512 + ch * TC + tl] = y;
    }
    __syncthreads();  // ybuf/hist/GxL/XS stable before next chunk
  }
  // single flush of y (the only global stores besides combine)
  ypout[tid] = ybuf[tid];
  ypout[512 + tid] = ybuf[512 + tid];
}

// ---------------- combine: out += yp1 + b_ffn ----------------
__global__ __launch_bounds__(256) void combine(const unsigned char* __restrict__ ws,
                                               const float* __restrict__ bffn,
                                               float* __restrict__ out) {
  int i = blockIdx.x * 256 + threadIdx.x;  // 0..131071
  const float* yp1 = (const float*)(ws + YP_OFF);
  out[i] = out[i] + yp1[i] + bffn[0];
}

extern "C" void kernel_launch(void* const* d_in, const int* in_sizes, int n_in,
                              void* d_out, int out_size, void* d_ws, size_t ws_size,
                              hipStream_t stream) {
  (void)in_sizes; (void)n_in; (void)out_size;
  const float* histX = (const float*)d_in[0];
  const float* futX  = (const float*)d_in[1];
  const float* WihH  = (const float*)d_in[2];
  const float* WhhH  = (const float*)d_in[3];
  const float* bihH  = (const float*)d_in[4];
  const float* bhhH  = (const float*)d_in[5];
  const float* WihF  = (const float*)d_in[6];
  const float* WhhF  = (const float*)d_in[7];
  const float* bihF  = (const float*)d_in[8];
  const float* bhhF  = (const float*)d_in[9];
  const float* Wffn  = (const float*)d_in[10];
  const float* bffn  = (const float*)d_in[11];
  unsigned char* ws = (unsigned char*)d_ws;
  float* out = (float*)d_out;

  if (ws_size < WS_NEEDED) return;

  prep<<<2048, 256, 0, stream>>>(WihH, WihF, WhhH, WhhF, ws);
  fused<<<dim3(B_ / 2, 2), 512, 0, stream>>>(histX, futX, bihH, bhhH, bihF, bhhF, Wffn, ws, out);
  combine<<<512, 256, 0, stream>>>(ws, bffn, out);
}